// Round 1
// baseline (326.396 us; speedup 1.0000x reference)
//
#include <hip/hip_runtime.h>

// AlphaCompositionShader: B=4,H=512,W=512,K=8.
// R2: one thread per PIXEL (was: one lane per fragment). Eliminates all ~30
// ds_bpermute (__shfl) ops per thread that made R1 LDS-latency-bound.
// Each thread reads its 8 fragments as per-thread-contiguous vectors
// (128B colors + 32B z + 32B labels -> every 128B line fully consumed
// within the wave), then does the whole scan in registers:
//   composite rgb = front-to-back: r += c_k*a_k*T ; T *= (1-a_k); r += bg*T
//   depth same with a'_k = (z_k>0 ? a_k : 0), bg=100
//   label = label of min k with (z>=0 && a>0.5), else -1
//   human[n] = front-most fragment with (z>=0 && lbl==n), over bg
// Outputs concatenated in d_out (float32), layout identical to R1:
//   [0,4P) image | [4P,5P) depth | [5P,6P) label | [6P,38P) human

#define BKG_DEPTH 100.0f
#define KD 8

__global__ __launch_bounds__(256) void alpha_comp_pixel(
    const float4* __restrict__ pc,   // P*8 rgba fragments
    const float4* __restrict__ zb4,  // P*2 (zbuf as float4)
    const int4*   __restrict__ lb4,  // P*2 (labels as int4)
    const float*  __restrict__ bg,   // 3 floats
    float* __restrict__ out,
    int P)
{
    const int p = blockIdx.x * blockDim.x + threadIdx.x;  // pixel idx
    if (p >= P) return;

    const float bg0 = bg[0], bg1 = bg[1], bg2 = bg[2];

    // ---- loads: per-thread contiguous, fully-consumed cache lines
    float4 c[KD];
    #pragma unroll
    for (int k = 0; k < KD; ++k) c[k] = pc[p * KD + k];

    const float4 zlo = zb4[p * 2 + 0];
    const float4 zhi = zb4[p * 2 + 1];
    const float z[KD] = {zlo.x, zlo.y, zlo.z, zlo.w, zhi.x, zhi.y, zhi.z, zhi.w};

    const int4 llo = lb4[p * 2 + 0];
    const int4 lhi = lb4[p * 2 + 1];
    const int l[KD] = {llo.x, llo.y, llo.z, llo.w, lhi.x, lhi.y, lhi.z, lhi.w};

    // ---- composite image (front-to-back closed form) + max alpha
    float T = 1.0f, r = 0.0f, g = 0.0f, b = 0.0f, am = 0.0f;
    #pragma unroll
    for (int k = 0; k < KD; ++k) {
        const float a = c[k].w;
        const float w = a * T;
        r = fmaf(c[k].x, w, r);
        g = fmaf(c[k].y, w, g);
        b = fmaf(c[k].z, w, b);
        am = fmaxf(am, a);
        T *= (1.0f - a);
    }
    r = fmaf(bg0, T, r);
    g = fmaf(bg1, T, g);
    b = fmaf(bg2, T, b);

    // ---- depth: layers with z>0 participate, others transparent
    float T2 = 1.0f, d = 0.0f;
    #pragma unroll
    for (int k = 0; k < KD; ++k) {
        const float a2 = (z[k] > 0.0f) ? c[k].w : 0.0f;
        d = fmaf(z[k] * a2, T2, d);
        T2 *= (1.0f - a2);
    }
    d = fmaf(BKG_DEPTH, T2, d);

    // ---- composite label: min k with (z>=0 && alpha>0.5), else -1
    float labv = -1.0f;
    #pragma unroll
    for (int k = KD - 1; k >= 0; --k) {
        const bool cond = (!(z[k] < 0.0f)) && (c[k].w > 0.5f);
        labv = cond ? (float)l[k] : labv;
    }

    // ---- fully coalesced pixel-granularity stores
    ((float4*)out)[p] = make_float4(r, g, b, am);
    out[(size_t)4 * P + p] = d;
    out[(size_t)5 * P + p] = labv;

    // ---- human images: for each label n, front-most valid fragment with l==n
    float4* __restrict__ hout = (float4*)(out + (size_t)6 * P);
    #pragma unroll
    for (int n = 0; n < KD; ++n) {
        float gx = 0.0f, gy = 0.0f, gz = 0.0f, gw = 0.0f;  // miss -> zeros -> bg over
        #pragma unroll
        for (int k = KD - 1; k >= 0; --k) {  // descending overwrite => min-k wins
            const bool m = (!(z[k] < 0.0f)) && (l[k] == n);
            gx = m ? c[k].x : gx;
            gy = m ? c[k].y : gy;
            gz = m ? c[k].z : gz;
            gw = m ? c[k].w : gw;
        }
        const float ia = 1.0f - gw;
        hout[p * KD + n] = make_float4(fmaf(gx, gw, bg0 * ia),
                                       fmaf(gy, gw, bg1 * ia),
                                       fmaf(gz, gw, bg2 * ia),
                                       gw);
    }
}

extern "C" void kernel_launch(void* const* d_in, const int* in_sizes, int n_in,
                              void* d_out, int out_size, void* d_ws, size_t ws_size,
                              hipStream_t stream) {
    const float4* pc  = (const float4*)d_in[0];  // pixel_colors (B,H,W,K,4) f32
    const float4* zb4 = (const float4*)d_in[1];  // zbuf (B,H,W,K) f32
    const int4*   lb4 = (const int4*)d_in[2];    // pixel_labels (B,H,W,K) i32
    const float*  bg  = (const float*)d_in[3];   // background_color (3,) f32
    float* out = (float*)d_out;

    const int P = in_sizes[1] / KD;              // B*H*W = 1048576
    const int block = 256;
    const int grid = (P + block - 1) / block;
    alpha_comp_pixel<<<grid, block, 0, stream>>>(pc, zb4, lb4, bg, out, P);
}

// Round 6
// 308.161 us; speedup vs baseline: 1.0592x; 1.0592x over previous
//
#include <hip/hip_runtime.h>

// AlphaCompositionShader: B=4,H=512,W=512,K=8.  P = B*H*W = 1048576 pixels.
// R3b (resubmit x3; GPU-acquisition timeouts, never measured):
// one thread per PIXEL for compute (zero cross-lane ops, as R2), but ALL
// large global streams are lane-consecutive (fully coalesced), transposed
// through LDS with a conflict-free XOR swizzle:
//   LDS slot (pl, j) holds fragment (pl, k = j ^ (pl&7)).
//   - stage-in:  lane-consecutive global float4 loads -> swizzled ds_write_b128
//   - read:      thread pl reads its 8 fragments at pl*8 + (k^(pl&7))
//     (each 8-lane group covers one full 128B row -> 0 bank conflicts)
//   - human out: thread writes 8 float4 to same swizzled slots, then block
//     stores lane-consecutive (nontemporal, 128 MiB stream).
// z / labels (64 MiB total) stay direct per-thread loads (16-line scatter, minor).
// Output layout identical to R1/R2:
//   [0,4P) image | [4P,5P) depth | [5P,6P) label | [6P,38P) human

#define BKG_DEPTH 100.0f
#define KD 8
#define BLK 256

typedef float f32x4 __attribute__((ext_vector_type(4)));  // nontemporal-storable

__global__ __launch_bounds__(256) void alpha_comp_lds(
    const float4* __restrict__ pc,   // P*8 rgba fragments
    const float4* __restrict__ zb4,  // P*2 (zbuf as float4)
    const int4*   __restrict__ lb4,  // P*2 (labels as int4)
    const float*  __restrict__ bg,   // 3 floats
    float* __restrict__ out,
    int P)
{
    __shared__ float4 cbuf[BLK * KD];      // 32 KiB: colors in, then human out

    const int t    = threadIdx.x;
    const int base = blockIdx.x * BLK;     // first pixel of this block
    const int p    = base + t;             // this thread's pixel
    const int pcl  = (p < P) ? p : (P - 1);

    const float bg0 = bg[0], bg1 = bg[1], bg2 = bg[2];

    // ---- z, labels: issue early, per-thread contiguous 32B (minor scatter)
    const float4 zlo = zb4[(size_t)pcl * 2 + 0];
    const float4 zhi = zb4[(size_t)pcl * 2 + 1];
    const int4   llo = lb4[(size_t)pcl * 2 + 0];
    const int4   lhi = lb4[(size_t)pcl * 2 + 1];

    // ---- stage colors: lane-consecutive loads -> swizzled LDS
    {
        const size_t fb = (size_t)base * KD;
        const size_t fmax = (size_t)P * KD - 1;
        float4 stg[8];
        #pragma unroll
        for (int i = 0; i < 8; ++i) {
            size_t g = fb + i * BLK + t;
            stg[i] = pc[g <= fmax ? g : fmax];
        }
        #pragma unroll
        for (int i = 0; i < 8; ++i) {
            const int g  = i * BLK + t;          // block-local fragment index
            const int pl = g >> 3;
            const int k  = g & 7;
            cbuf[pl * KD + (k ^ (pl & 7))] = stg[i];
        }
    }
    __syncthreads();

    // ---- read own pixel's fragments (conflict-free swizzled ds_read_b128)
    float4 c[KD];
    #pragma unroll
    for (int k = 0; k < KD; ++k)
        c[k] = cbuf[t * KD + (k ^ (t & 7))];
    __syncthreads();                        // cbuf now reusable for human out

    const float z[KD] = {zlo.x, zlo.y, zlo.z, zlo.w, zhi.x, zhi.y, zhi.z, zhi.w};
    const int   l[KD] = {llo.x, llo.y, llo.z, llo.w, lhi.x, lhi.y, lhi.z, lhi.w};

    // ---- composite image (front-to-back closed form) + max alpha
    float T = 1.0f, r = 0.0f, g = 0.0f, b = 0.0f, am = 0.0f;
    #pragma unroll
    for (int k = 0; k < KD; ++k) {
        const float a = c[k].w;
        const float w = a * T;
        r = fmaf(c[k].x, w, r);
        g = fmaf(c[k].y, w, g);
        b = fmaf(c[k].z, w, b);
        am = fmaxf(am, a);
        T *= (1.0f - a);
    }
    r = fmaf(bg0, T, r);
    g = fmaf(bg1, T, g);
    b = fmaf(bg2, T, b);

    // ---- depth: layers with z>0 participate, others transparent
    float T2 = 1.0f, d = 0.0f;
    #pragma unroll
    for (int k = 0; k < KD; ++k) {
        const float a2 = (z[k] > 0.0f) ? c[k].w : 0.0f;
        d = fmaf(z[k] * a2, T2, d);
        T2 *= (1.0f - a2);
    }
    d = fmaf(BKG_DEPTH, T2, d);

    // ---- composite label: min k with (z>=0 && alpha>0.5), else -1
    float labv = -1.0f;
    #pragma unroll
    for (int k = KD - 1; k >= 0; --k) {
        const bool cond = (!(z[k] < 0.0f)) && (c[k].w > 0.5f);
        labv = cond ? (float)l[k] : labv;
    }

    // ---- pixel-granularity stores (fully coalesced across the wave)
    if (p < P) {
        ((float4*)out)[p] = make_float4(r, g, b, am);
        out[(size_t)4 * P + p] = d;
        out[(size_t)5 * P + p] = labv;
    }

    // ---- human images: front-most valid fragment with l==n, staged to LDS
    #pragma unroll
    for (int n = 0; n < KD; ++n) {
        float gx = 0.0f, gy = 0.0f, gz = 0.0f, gw = 0.0f;  // miss -> bg over 0
        #pragma unroll
        for (int k = KD - 1; k >= 0; --k) {   // descending overwrite => min-k wins
            const bool m = (!(z[k] < 0.0f)) && (l[k] == n);
            gx = m ? c[k].x : gx;
            gy = m ? c[k].y : gy;
            gz = m ? c[k].z : gz;
            gw = m ? c[k].w : gw;
        }
        const float ia = 1.0f - gw;
        cbuf[t * KD + (n ^ (t & 7))] = make_float4(fmaf(gx, gw, bg0 * ia),
                                                   fmaf(gy, gw, bg1 * ia),
                                                   fmaf(gz, gw, bg2 * ia),
                                                   gw);
    }
    __syncthreads();

    // ---- human store-out: swizzled LDS read -> lane-consecutive nontemporal store
    {
        f32x4* __restrict__ hout = (f32x4*)(out + (size_t)6 * P);
        const size_t fb = (size_t)base * KD;
        #pragma unroll
        for (int i = 0; i < 8; ++i) {
            const int g  = i * BLK + t;          // block-local fragment index
            const int pl = g >> 3;
            const int n  = g & 7;
            const float4 v = cbuf[pl * KD + (n ^ (pl & 7))];
            const size_t go = fb + g;
            if (go < (size_t)P * KD) {
                f32x4 vv = {v.x, v.y, v.z, v.w};
                __builtin_nontemporal_store(vv, &hout[go]);
            }
        }
    }
}

extern "C" void kernel_launch(void* const* d_in, const int* in_sizes, int n_in,
                              void* d_out, int out_size, void* d_ws, size_t ws_size,
                              hipStream_t stream) {
    const float4* pc  = (const float4*)d_in[0];  // pixel_colors (B,H,W,K,4) f32
    const float4* zb4 = (const float4*)d_in[1];  // zbuf (B,H,W,K) f32
    const int4*   lb4 = (const int4*)d_in[2];    // pixel_labels (B,H,W,K) i32
    const float*  bg  = (const float*)d_in[3];   // background_color (3,) f32
    float* out = (float*)d_out;

    const int P = in_sizes[1] / KD;              // B*H*W = 1048576
    const int block = BLK;
    const int grid = (P + block - 1) / block;
    alpha_comp_lds<<<grid, block, 0, stream>>>(pc, zb4, lb4, bg, out, P);
}

// Round 7
// 296.543 us; speedup vs baseline: 1.1007x; 1.0392x over previous
//
#include <hip/hip_runtime.h>

// AlphaCompositionShader: B=4,H=512,W=512,K=8.  P = B*H*W = 1048576 pixels.
// R4: R1's memory engine (8 lanes per pixel, one lane per fragment, everything
// naturally lane-consecutive, NO LDS, NO barriers, 8.4M threads keeping loads
// in flight) with the LDS-pipe cost removed: all width-8 scans/reductions now
// use DPP (VALU-speed) instead of ds_bpermute:
//   __shfl_up(x,s,8)  -> v_mov_dpp row_shr:s   (predicate kk>=s == group-exact)
//   __shfl_xor(x,1/2) -> quad_perm 0xB1 / 0x4E
//   cross-half combine-> row_shl:4 (valid kk<4) / row_shr:4 (valid kk>=4)
//   T broadcast k7->k0/k1 -> row_shl:7 / row_shl:6
// Labels (0..7) packed as nibbles into one 32-bit word, OR-reduced via DPP:
// composite-label select and human-image search become register bit-ops.
// Only 4 ds_bpermute remain (human float4 gather). All stores nontemporal.
// Output layout identical to prior rounds:
//   [0,4P) image | [4P,5P) depth | [5P,6P) label | [6P,38P) human

#define BKG_DEPTH 100.0f
#define KD 8

typedef float f32x4 __attribute__((ext_vector_type(4)));

#define QP_XOR1 0xB1            // quad_perm [1,0,3,2]
#define QP_XOR2 0x4E            // quad_perm [2,3,0,1]
#define ROW_SHL(n) (0x100 | (n))  // dst lane r <- src lane r+n (within 16-row)
#define ROW_SHR(n) (0x110 | (n))  // dst lane r <- src lane r-n (within 16-row)

template <int CTRL>
__device__ __forceinline__ float dppf(float x) {
    return __int_as_float(__builtin_amdgcn_update_dpp(
        0, __float_as_int(x), CTRL, 0xF, 0xF, true));
}
template <int CTRL>
__device__ __forceinline__ int dppi(int x) {
    return __builtin_amdgcn_update_dpp(0, x, CTRL, 0xF, 0xF, true);
}

__global__ __launch_bounds__(256) void alpha_comp_dpp(
    const float4* __restrict__ pc,   // P*8 rgba fragments
    const float*  __restrict__ zb,   // P*8 z
    const int*    __restrict__ lb,   // P*8 labels (0..7)
    const float*  __restrict__ bg,   // 3 floats
    float* __restrict__ out,
    int P)
{
    const int tid = blockIdx.x * blockDim.x + threadIdx.x;  // global fragment idx
    const int pix = tid >> 3;
    const int kk  = tid & 7;                                // fragment k == human label n
    if (pix >= P) return;                                   // grid is exact; safety only

    const float bg0 = bg[0], bg1 = bg[1], bg2 = bg[2];

    // ---- fully coalesced loads (lane-consecutive, 24 B/lane)
    const float4 c     = pc[tid];
    const float  z     = zb[tid];
    const int    lbl   = lb[tid];
    const float  alpha = c.w;
    const bool   valid = !(z < 0.0f);

    // ---- inclusive prefix product of (1-a) via DPP scan (3 steps)
    float incl = 1.0f - alpha;
    { const float u = dppf<ROW_SHR(1)>(incl); incl = (kk >= 1) ? incl * u : incl; }
    { const float u = dppf<ROW_SHR(2)>(incl); incl = (kk >= 2) ? incl * u : incl; }
    { const float u = dppf<ROW_SHR(4)>(incl); incl = (kk >= 4) ? incl * u : incl; }
    float pre = dppf<ROW_SHR(1)>(incl); pre = (kk == 0) ? 1.0f : pre;  // exclusive
    const float T = dppf<ROW_SHL(7)>(incl);   // full product, valid in lane kk==0
    const float w = alpha * pre;

    // ---- rgb weighted sums + max alpha (totals valid in kk<4 after combine)
    float sr = c.x * w, sg = c.y * w, sb = c.z * w, am = alpha;
    sr += dppf<QP_XOR1>(sr); sg += dppf<QP_XOR1>(sg); sb += dppf<QP_XOR1>(sb);
    am = fmaxf(am, dppf<QP_XOR1>(am));
    sr += dppf<QP_XOR2>(sr); sg += dppf<QP_XOR2>(sg); sb += dppf<QP_XOR2>(sb);
    am = fmaxf(am, dppf<QP_XOR2>(am));
    sr += dppf<ROW_SHL(4)>(sr); sg += dppf<ROW_SHL(4)>(sg); sb += dppf<ROW_SHL(4)>(sb);
    am = fmaxf(am, dppf<ROW_SHL(4)>(am));    // fmax(x,0) harmless in unused lanes

    // ---- depth: layers with z>0 participate, others transparent
    const float a2 = (z > 0.0f) ? alpha : 0.0f;
    float incl2 = 1.0f - a2;
    { const float u = dppf<ROW_SHR(1)>(incl2); incl2 = (kk >= 1) ? incl2 * u : incl2; }
    { const float u = dppf<ROW_SHR(2)>(incl2); incl2 = (kk >= 2) ? incl2 * u : incl2; }
    { const float u = dppf<ROW_SHR(4)>(incl2); incl2 = (kk >= 4) ? incl2 * u : incl2; }
    float pre2 = dppf<ROW_SHR(1)>(incl2); pre2 = (kk == 0) ? 1.0f : pre2;
    const float T2 = dppf<ROW_SHL(6)>(incl2); // full product, valid in lane kk==1
    float sd = z * (a2 * pre2);               // 0 when a2==0
    sd += dppf<QP_XOR1>(sd);
    sd += dppf<QP_XOR2>(sd);
    sd += dppf<ROW_SHL(4)>(sd);               // total valid in kk<4
    const float outD = fmaf(BKG_DEPTH, T2, sd);

    // ---- pack all 8 labels as nibbles into one word (every lane gets full word)
    int pw = (valid ? lbl : 0xF) << (4 * kk);
    pw |= dppi<QP_XOR1>(pw);
    pw |= dppi<QP_XOR2>(pw);
    {
        const int lo = dppi<ROW_SHL(4)>(pw);  // other quad, valid for kk<4
        const int hi = dppi<ROW_SHR(4)>(pw);  // other quad, valid for kk>=4
        pw |= (kk & 4) ? hi : lo;
    }

    // ---- composite label: min k with (valid && alpha>0.5), else -1
    const unsigned long long bal = __ballot(valid && (alpha > 0.5f));
    const int lane = threadIdx.x & 63;
    const unsigned grpByte = (unsigned)((bal >> (lane & ~7)) & 0xFFull);
    const int jlab = grpByte ? (__ffs(grpByte) - 1) : 0;
    const float labv = grpByte ? (float)((pw >> (4 * jlab)) & 0xF) : -1.0f;

    // ---- human image for label n = kk: front-most fragment with nibble==kk
    int jm = 8;                                // sentinel: no hit
    #pragma unroll
    for (int j = 7; j >= 0; --j)
        jm = (((pw >> (4 * j)) & 0xF) == kk) ? j : jm;
    const bool hit = (jm < 8);
    const int src = hit ? jm : 0;
    float gx = __shfl(c.x, src, 8);            // the only 4 ds_bpermute ops
    float gy = __shfl(c.y, src, 8);
    float gz = __shfl(c.z, src, 8);
    float gw = __shfl(c.w, src, 8);
    gx = hit ? gx : 0.0f;  gy = hit ? gy : 0.0f;
    gz = hit ? gz : 0.0f;  gw = hit ? gw : 0.0f;
    const float ia = 1.0f - gw;
    const f32x4 hv = { fmaf(gx, gw, bg0 * ia),
                       fmaf(gy, gw, bg1 * ia),
                       fmaf(gz, gw, bg2 * ia),
                       gw };

    // ---- stores (all streams lane-consecutive or dense; nontemporal)
    __builtin_nontemporal_store(hv, &((f32x4*)(out + (size_t)6 * P))[tid]);
    if (kk == 0) {
        const f32x4 img = { fmaf(bg0, T, sr), fmaf(bg1, T, sg), fmaf(bg2, T, sb), am };
        __builtin_nontemporal_store(img, &((f32x4*)out)[pix]);
    }
    if (kk == 1) __builtin_nontemporal_store(outD, &out[(size_t)4 * P + pix]);
    if (kk == 2) __builtin_nontemporal_store(labv, &out[(size_t)5 * P + pix]);
}

extern "C" void kernel_launch(void* const* d_in, const int* in_sizes, int n_in,
                              void* d_out, int out_size, void* d_ws, size_t ws_size,
                              hipStream_t stream) {
    const float4* pc = (const float4*)d_in[0];   // pixel_colors (B,H,W,K,4) f32
    const float*  zb = (const float*)d_in[1];    // zbuf (B,H,W,K) f32
    const int*    lb = (const int*)d_in[2];      // pixel_labels (B,H,W,K) i32
    const float*  bg = (const float*)d_in[3];    // background_color (3,) f32
    float* out = (float*)d_out;

    const int P = in_sizes[1] / KD;              // B*H*W = 1048576
    const int total = P * KD;                    // one thread per fragment
    const int block = 256;
    const int grid = (total + block - 1) / block;
    alpha_comp_dpp<<<grid, block, 0, stream>>>(pc, zb, lb, bg, out, P);
}